// Round 13
// baseline (649.869 us; speedup 1.0000x reference)
//
#include <hip/hip_runtime.h>
#include <math.h>

#define NN 50000
#define NE 800000

typedef __attribute__((ext_vector_type(8))) short  s16x8;  // 8 bf16 (4 VGPRs) MFMA A/B frag
typedef __attribute__((ext_vector_type(4))) float  f32x4;  // MFMA C/D frag

__device__ __forceinline__ float silu(float x) { return x / (1.0f + expf(-x)); }

__device__ __forceinline__ unsigned short f2bf(float f) {  // RNE f32->bf16
    unsigned u = __builtin_bit_cast(unsigned, f);
    u += 0x7FFFu + ((u >> 16) & 1u);
    return (unsigned short)(u >> 16);
}
__device__ __forceinline__ float bf2f(unsigned short b) {
    unsigned u = ((unsigned)b) << 16;
    return __builtin_bit_cast(float, u);
}

// Zero-cost ordering fence: forbids compiler reordering of LDS ops across it.
// HW DS pipe is in-order per wave.
__device__ __forceinline__ void wave_fence() {
    asm volatile("" ::: "memory");
    __builtin_amdgcn_wave_barrier();
    asm volatile("" ::: "memory");
}

#define GP 72    // K pitch (bf16) for 64-K tiles
#define OP 136   // K pitch (bf16) for 128-K tiles (node_out)

// ---------------- Kernel 1: per-node gates via MFMA (16 nodes/wave)
__global__ __launch_bounds__(256, 4) void node_gate_kernel(
    const float* __restrict__ h,
    const float* __restrict__ nx_w1, const float* __restrict__ nx_b1,
    const float* __restrict__ nx_w2, const float* __restrict__ nx_b2,
    const float* __restrict__ nv_w1, const float* __restrict__ nv_b1,
    const float* __restrict__ nv_w2, const float* __restrict__ nv_b2,
    float* __restrict__ gx, float* __restrict__ gv)
{
    __shared__ unsigned short At[4][16 * GP];
    int tid = threadIdx.x;
    int wv = tid >> 6, l = tid & 63;
    int lm = l & 15, lg = l >> 4;

    s16x8 BX[2][4], BV[2][4];
    float bx1v[4], bv1v[4], wx2v[4], wv2v[4];
    #pragma unroll
    for (int ns = 0; ns < 4; ++ns) {
        int n = 16 * ns + lm;
        bx1v[ns] = nx_b1[n]; bv1v[ns] = nv_b1[n];
        wx2v[ns] = nx_w2[n]; wv2v[ns] = nv_w2[n];
        #pragma unroll
        for (int kk = 0; kk < 2; ++kk) {
            s16x8 bx, bv;
            #pragma unroll
            for (int j = 0; j < 8; ++j) {
                int k = 32 * kk + 8 * lg + j;
                bx[j] = (short)f2bf(nx_w1[k * 64 + n]);
                bv[j] = (short)f2bf(nv_w1[k * 64 + n]);
            }
            BX[kk][ns] = bx; BV[kk][ns] = bv;
        }
    }
    float bx2 = nx_b2[0], bv2 = nv_b2[0];
    unsigned short* A = At[wv];

    const int ntile = NN / 16;
    for (int tile = blockIdx.x * 4 + wv; tile < ntile; tile += gridDim.x * 4) {
        int base = tile * 16;
        #pragma unroll 4
        for (int e = 0; e < 16; ++e)
            A[e * GP + l] = f2bf(h[(long)(base + e) * 64 + l]);
        wave_fence();

        f32x4 ax[4], av[4];
        #pragma unroll
        for (int ns = 0; ns < 4; ++ns) {
            float bx = bx1v[ns], bv = bv1v[ns];
            ax[ns] = (f32x4){bx, bx, bx, bx};
            av[ns] = (f32x4){bv, bv, bv, bv};
        }
        #pragma unroll
        for (int kk = 0; kk < 2; ++kk) {
            s16x8 af = *(const s16x8*)&A[lm * GP + 32 * kk + 8 * lg];
            #pragma unroll
            for (int ns = 0; ns < 4; ++ns) {
                ax[ns] = __builtin_amdgcn_mfma_f32_16x16x32_bf16(af, BX[kk][ns], ax[ns], 0, 0, 0);
                av[ns] = __builtin_amdgcn_mfma_f32_16x16x32_bf16(af, BV[kk][ns], av[ns], 0, 0, 0);
            }
        }
        #pragma unroll
        for (int i = 0; i < 4; ++i) {
            float px = 0.0f, pv = 0.0f;
            #pragma unroll
            for (int ns = 0; ns < 4; ++ns) {
                px += silu(ax[ns][i]) * wx2v[ns];
                pv += silu(av[ns][i]) * wv2v[ns];
            }
            px += __shfl_xor(px, 1); pv += __shfl_xor(pv, 1);
            px += __shfl_xor(px, 2); pv += __shfl_xor(pv, 2);
            px += __shfl_xor(px, 4); pv += __shfl_xor(pv, 4);
            px += __shfl_xor(px, 8); pv += __shfl_xor(pv, 8);
            if (lm == 0) {
                gx[base + 4 * lg + i] = px + bx2;
                gv[base + 4 * lg + i] = pv + bv2;
            }
        }
        wave_fence();
    }
}

// ---------------- Kernel 2: edge MLPs via MFMA + atomic scatter (hot kernel)
// T14 async-STAGE: next-tile loads issue in registers during current-tile
// compute; the vmcnt wait lands after a full GEMM phase, not at issue.
#define KPAD   168   // A / w1t K stride (bf16)
#define YPITCH 72    // Y K stride (bf16)

__global__ __launch_bounds__(256, 3) void edge_kernel(
    const float* __restrict__ x, const float* __restrict__ h, const float* __restrict__ v,
    const int* __restrict__ row, const int* __restrict__ col,
    const float* __restrict__ edge_fea,
    const float* __restrict__ em_w1, const float* __restrict__ em_b1,
    const float* __restrict__ em_w2, const float* __restrict__ em_b2,
    const float* __restrict__ cn_w1, const float* __restrict__ cn_b1,
    const float* __restrict__ cn_w2, const float* __restrict__ cn_b2,
    float* __restrict__ cnt, double* __restrict__ totf, float* __restrict__ totmsg)
{
    __shared__ unsigned short w1t[64 * KPAD];     // [n][k'] = em_w1[orig(k')][n], bf16
    __shared__ float b1s[64], b2s[64], cb1s[64], c2s[64];
    __shared__ unsigned short Atile[4][16 * KPAD];
    __shared__ unsigned short Ybuf [4][16 * YPITCH];

    int tid = threadIdx.x;
    for (int idx = tid; idx < 64 * KPAD; idx += 256) {
        int n = idx / KPAD, kp = idx - n * KPAD;
        float val = 0.0f;
        if (kp < 146) { int ko = (kp < 144) ? (kp + 2) : (kp - 144); val = em_w1[ko * 64 + n]; }
        w1t[n * KPAD + kp] = f2bf(val);
    }
    if (tid < 64) { b1s[tid] = em_b1[tid]; b2s[tid] = em_b2[tid]; cb1s[tid] = cn_b1[tid]; c2s[tid] = cn_w2[tid]; }
    __syncthreads();
    float cb2 = cn_b2[0];

    int wv = tid >> 6, l = tid & 63;
    int lm = l & 15, lg = l >> 4;

    s16x8 B2[2][4], B3[2][4];
    #pragma unroll
    for (int kk = 0; kk < 2; ++kk)
        #pragma unroll
        for (int ns = 0; ns < 4; ++ns) {
            int n = 16 * ns + lm;
            s16x8 b2v, b3v;
            #pragma unroll
            for (int j = 0; j < 8; ++j) {
                int k = 32 * kk + 8 * lg + j;
                b2v[j] = (short)f2bf(em_w2[k * 64 + n]);
                b3v[j] = (short)f2bf(cn_w1[k * 64 + n]);
            }
            B2[kk][ns] = b2v; B3[kk][ns] = b3v;
        }

    unsigned short* A = Atile[wv];
    unsigned short* Y = Ybuf[wv];

    if (lg == 0)
        for (int z = 146; z < KPAD; ++z) A[lm * KPAD + z] = 0;
    wave_fence();

    const int ntile  = NE / 16;
    const int stride = gridDim.x * 4;
    int tile = blockIdx.x * 4 + wv;

    // ---- prefetch registers (full-unroll static indexing only)
    int   pr_r = 0, pr_c = 0;
    float pg[12];                 // x[r]3, x[c]3, v[r]3, v[c]3
    float ph_r[16], ph_c[16];     // gathered h rows (own lane column)
    float pef[4];

    // ---- prologue: full prefetch of first tile
    if (tile < ntile) {
        int base = tile * 16;
        pr_r = row[base + lm]; pr_c = col[base + lm];
        const float* efb = edge_fea + (long)base * 16;
        #pragma unroll
        for (int i = 0; i < 4; ++i) pef[i] = efb[i * 64 + l];
        #pragma unroll
        for (int i = 0; i < 3; ++i) {
            pg[i]     = x[(long)pr_r * 3 + i];
            pg[3 + i] = x[(long)pr_c * 3 + i];
            pg[6 + i] = v[(long)pr_r * 3 + i];
            pg[9 + i] = v[(long)pr_c * 3 + i];
        }
        #pragma unroll
        for (int e = 0; e < 16; ++e) {
            int re = __shfl(pr_r, e);
            int ce = __shfl(pr_c, e);
            ph_r[e] = h[(long)re * 64 + l];
            ph_c[e] = h[(long)ce * 64 + l];
        }
    }

    for (; tile < ntile; tile += stride) {
        // ---- consume prefetch: current-tile scalars
        int r_own = pr_r;
        float rx = pg[0] - pg[3], ry = pg[1] - pg[4], rz = pg[2] - pg[5];
        float sx = pg[6] - pg[9], sy = pg[7] - pg[10], sz = pg[8] - pg[11];
        float nr  = sqrtf(rx * rx + ry * ry + rz * rz);
        float nsv = sqrtf(sx * sx + sy * sy + sz * sz);

        // ---- STAGE regs -> LDS (bf16)
        #pragma unroll
        for (int e = 0; e < 16; ++e) {
            A[e * KPAD + l]      = f2bf(ph_r[e]);
            A[e * KPAD + 64 + l] = f2bf(ph_c[e]);
        }
        #pragma unroll
        for (int i = 0; i < 4; ++i) {
            int idx = i * 64 + l; int e = idx >> 4, j = idx & 15;
            A[e * KPAD + 128 + j] = f2bf(pef[i]);
        }
        if (lg == 0) {
            A[lm * KPAD + 144] = f2bf(nr);
            A[lm * KPAD + 145] = f2bf(nsv);
        }
        wave_fence();

        // ---- prefetch (independent part): next-tile idx + edge_fea
        int nt = tile + stride;
        bool havenext = nt < ntile;
        if (havenext) {
            int nb = nt * 16;
            pr_r = row[nb + lm]; pr_c = col[nb + lm];
            const float* efb = edge_fea + (long)nb * 16;
            #pragma unroll
            for (int i = 0; i < 4; ++i) pef[i] = efb[i * 64 + l];
        }

        // ---- GEMM1: [16 x 160] x [160 x 64]
        f32x4 acc[4];
        #pragma unroll
        for (int ns = 0; ns < 4; ++ns) { float b = b1s[16 * ns + lm]; acc[ns] = (f32x4){b, b, b, b}; }
        #pragma unroll
        for (int kk = 0; kk < 5; ++kk) {
            s16x8 af = *(const s16x8*)&A[lm * KPAD + 32 * kk + 8 * lg];
            #pragma unroll
            for (int ns = 0; ns < 4; ++ns) {
                s16x8 bf = *(const s16x8*)&w1t[(16 * ns + lm) * KPAD + 32 * kk + 8 * lg];
                acc[ns] = __builtin_amdgcn_mfma_f32_16x16x32_bf16(af, bf, acc[ns], 0, 0, 0);
            }
        }
        wave_fence();  // orders prior scatter Y-reads before Y writes below
        #pragma unroll
        for (int ns = 0; ns < 4; ++ns)
            #pragma unroll
            for (int i = 0; i < 4; ++i)
                Y[(4 * lg + i) * YPITCH + 16 * ns + lm] = f2bf(silu(acc[ns][i]));
        wave_fence();

        // ---- prefetch (dependent part): next-tile geometry + h gather
        if (havenext) {
            #pragma unroll
            for (int i = 0; i < 3; ++i) {
                pg[i]     = x[(long)pr_r * 3 + i];
                pg[3 + i] = x[(long)pr_c * 3 + i];
                pg[6 + i] = v[(long)pr_r * 3 + i];
                pg[9 + i] = v[(long)pr_c * 3 + i];
            }
            #pragma unroll
            for (int e = 0; e < 16; ++e) {
                int re = __shfl(pr_r, e);
                int ce = __shfl(pr_c, e);
                ph_r[e] = h[(long)re * 64 + l];
                ph_c[e] = h[(long)ce * 64 + l];
            }
        }

        // ---- GEMM2: y[16x64] x em_w2 -> message (silu)
        #pragma unroll
        for (int ns = 0; ns < 4; ++ns) { float b = b2s[16 * ns + lm]; acc[ns] = (f32x4){b, b, b, b}; }
        #pragma unroll
        for (int kk = 0; kk < 2; ++kk) {
            s16x8 af = *(const s16x8*)&Y[lm * YPITCH + 32 * kk + 8 * lg];
            #pragma unroll
            for (int ns = 0; ns < 4; ++ns)
                acc[ns] = __builtin_amdgcn_mfma_f32_16x16x32_bf16(af, B2[kk][ns], acc[ns], 0, 0, 0);
        }
        wave_fence();  // GEMM2 A-reads done before Y overwrite
        #pragma unroll
        for (int ns = 0; ns < 4; ++ns)
            #pragma unroll
            for (int i = 0; i < 4; ++i)
                Y[(4 * lg + i) * YPITCH + 16 * ns + lm] = f2bf(silu(acc[ns][i]));
        wave_fence();

        // ---- GEMM3: msg[16x64] x cn_w1 -> t; cm = dot(silu(t), cn_w2) + cb2
        #pragma unroll
        for (int ns = 0; ns < 4; ++ns) { float b = cb1s[16 * ns + lm]; acc[ns] = (f32x4){b, b, b, b}; }
        #pragma unroll
        for (int kk = 0; kk < 2; ++kk) {
            s16x8 af = *(const s16x8*)&Y[lm * YPITCH + 32 * kk + 8 * lg];
            #pragma unroll
            for (int ns = 0; ns < 4; ++ns)
                acc[ns] = __builtin_amdgcn_mfma_f32_16x16x32_bf16(af, B3[kk][ns], acc[ns], 0, 0, 0);
        }
        float cm[4];
        #pragma unroll
        for (int i = 0; i < 4; ++i) {
            float p = 0.0f;
            #pragma unroll
            for (int ns = 0; ns < 4; ++ns) p += silu(acc[ns][i]) * c2s[16 * ns + lm];
            p += __shfl_xor(p, 1); p += __shfl_xor(p, 2);
            p += __shfl_xor(p, 4); p += __shfl_xor(p, 8);
            cm[i] = p + cb2;
        }

        // ---- scatter tot_f (f64) + cnt
        #pragma unroll
        for (int i = 0; i < 4; ++i) {
            int e = 4 * lg + i;
            float rxe = __shfl(rx, e), rye = __shfl(ry, e), rze = __shfl(rz, e);
            int   re  = __shfl(r_own, e);
            if (lm < 3) {
                float comp = (lm == 0) ? rxe : (lm == 1) ? rye : rze;
                atomicAdd(&totf[(long)re * 3 + lm], (double)(comp * cm[i]));
            } else if (lm == 3) {
                atomicAdd(&cnt[re], 1.0f);
            }
        }
        // ---- scatter tot_message (coalesced 256B per edge)
        #pragma unroll 4
        for (int e = 0; e < 16; ++e) {
            int re = __shfl(r_own, e);
            float mval = bf2f(Y[e * YPITCH + l]);
            atomicAdd(&totmsg[(long)re * 64 + l], mval);
        }
    }
}

// ---------------- Kernel 3: finalize nodes via MFMA (16 nodes/wave)
__global__ __launch_bounds__(256, 3) void node_out_kernel(
    const float* __restrict__ x, const float* __restrict__ h, const float* __restrict__ v,
    const float* __restrict__ nn_w1, const float* __restrict__ nn_b1,
    const float* __restrict__ nn_w2, const float* __restrict__ nn_b2,
    const float* __restrict__ cnt, const double* __restrict__ totf,
    const float* __restrict__ totmsg,
    const float* __restrict__ gx, const float* __restrict__ gv,
    float* __restrict__ xout, float* __restrict__ vout, float* __restrict__ hout)
{
    __shared__ unsigned short w1t[64 * OP];
    __shared__ unsigned short At[4][16 * OP];
    __shared__ unsigned short Yt[4][16 * GP];

    int tid = threadIdx.x;
    for (int idx = tid; idx < 64 * OP; idx += 256) {
        int n = idx / OP, k = idx - n * OP;
        w1t[idx] = f2bf(k < 128 ? nn_w1[k * 64 + n] : 0.0f);
    }
    __syncthreads();

    int wv = tid >> 6, l = tid & 63;
    int lm = l & 15, lg = l >> 4;

    s16x8 B2[2][4];
    float b1v[4], b2v[4];
    #pragma unroll
    for (int ns = 0; ns < 4; ++ns) {
        int n = 16 * ns + lm;
        b1v[ns] = nn_b1[n]; b2v[ns] = nn_b2[n];
        #pragma unroll
        for (int kk = 0; kk < 2; ++kk) {
            s16x8 b;
            #pragma unroll
            for (int j = 0; j < 8; ++j)
                b[j] = (short)f2bf(nn_w2[(32 * kk + 8 * lg + j) * 64 + n]);
            B2[kk][ns] = b;
        }
    }

    unsigned short* A = At[wv];
    unsigned short* Y = Yt[wv];

    const int ntile = NN / 16;
    for (int tile = blockIdx.x * 4 + wv; tile < ntile; tile += gridDim.x * 4) {
        int base = tile * 16;
        #pragma unroll 4
        for (int e = 0; e < 16; ++e) {
            A[e * OP + l]      = f2bf(h[(long)(base + e) * 64 + l]);
            A[e * OP + 64 + l] = f2bf(totmsg[(long)(base + e) * 64 + l]);
        }
        wave_fence();

        f32x4 acc[4];
        #pragma unroll
        for (int ns = 0; ns < 4; ++ns) { float b = b1v[ns]; acc[ns] = (f32x4){b, b, b, b}; }
        #pragma unroll
        for (int kk = 0; kk < 4; ++kk) {
            s16x8 af = *(const s16x8*)&A[lm * OP + 32 * kk + 8 * lg];
            #pragma unroll
            for (int ns = 0; ns < 4; ++ns) {
                s16x8 bf = *(const s16x8*)&w1t[(16 * ns + lm) * OP + 32 * kk + 8 * lg];
                acc[ns] = __builtin_amdgcn_mfma_f32_16x16x32_bf16(af, bf, acc[ns], 0, 0, 0);
            }
        }
        wave_fence();
        #pragma unroll
        for (int ns = 0; ns < 4; ++ns)
            #pragma unroll
            for (int i = 0; i < 4; ++i)
                Y[(4 * lg + i) * GP + 16 * ns + lm] = f2bf(silu(acc[ns][i]));
        wave_fence();

        #pragma unroll
        for (int ns = 0; ns < 4; ++ns) { float b = b2v[ns]; acc[ns] = (f32x4){b, b, b, b}; }
        #pragma unroll
        for (int kk = 0; kk < 2; ++kk) {
            s16x8 af = *(const s16x8*)&Y[lm * GP + 32 * kk + 8 * lg];
            #pragma unroll
            for (int ns = 0; ns < 4; ++ns)
                acc[ns] = __builtin_amdgcn_mfma_f32_16x16x32_bf16(af, B2[kk][ns], acc[ns], 0, 0, 0);
        }
        #pragma unroll
        for (int ns = 0; ns < 4; ++ns)
            #pragma unroll
            for (int i = 0; i < 4; ++i)
                hout[(long)(base + 4 * lg + i) * 64 + 16 * ns + lm] = acc[ns][i];

        if (l < 48) {
            int nd = base + l / 3, c = l - (l / 3) * 3;
            double dn = fmax((double)cnt[nd], 1.0);
            double tf = totf[(long)nd * 3 + c] / dn;
            tf = fmin(fmax(tf, -100.0), 100.0);
            xout[(long)nd * 3 + c] = gx[nd] * x[(long)nd * 3 + c] + (float)tf;
            vout[(long)nd * 3 + c] = gv[nd] * v[(long)nd * 3 + c] + (float)tf;
        }
        wave_fence();
    }
}

extern "C" void kernel_launch(void* const* d_in, const int* in_sizes, int n_in,
                              void* d_out, int out_size, void* d_ws, size_t ws_size,
                              hipStream_t stream) {
    const float* x        = (const float*)d_in[0];
    const float* h        = (const float*)d_in[1];
    const float* v        = (const float*)d_in[2];
    const int*   eidx     = (const int*)d_in[3];
    const float* edge_fea = (const float*)d_in[4];
    const float* em_w1 = (const float*)d_in[5];  const float* em_b1 = (const float*)d_in[6];
    const float* em_w2 = (const float*)d_in[7];  const float* em_b2 = (const float*)d_in[8];
    const float* cn_w1 = (const float*)d_in[9];  const float* cn_b1 = (const float*)d_in[10];
    const float* cn_w2 = (const float*)d_in[11]; const float* cn_b2 = (const float*)d_in[12];
    const float* nn_w1 = (const float*)d_in[13]; const float* nn_b1 = (const float*)d_in[14];
    const float* nn_w2 = (const float*)d_in[15]; const float* nn_b2 = (const float*)d_in[16];
    const float* nx_w1 = (const float*)d_in[17]; const float* nx_b1 = (const float*)d_in[18];
    const float* nx_w2 = (const float*)d_in[19]; const float* nx_b2 = (const float*)d_in[20];
    const float* nv_w1 = (const float*)d_in[21]; const float* nv_b1 = (const float*)d_in[22];
    const float* nv_w2 = (const float*)d_in[23]; const float* nv_b2 = (const float*)d_in[24];

    const int* row = eidx;
    const int* col = eidx + NE;

    float*  ws     = (float*)d_ws;
    float*  cnt    = ws;
    float*  gx     = ws + NN;
    float*  gv     = ws + 2 * NN;
    float*  totmsg = ws + 3 * NN;
    double* totf   = (double*)(ws + 68 * NN);

    float* xout = (float*)d_out;
    float* vout = xout + NN * 3;
    float* hout = vout + NN * 3;

    hipMemsetAsync(d_ws, 0, (size_t)74 * NN * sizeof(float), stream);

    node_gate_kernel<<<1024, 256, 0, stream>>>(h, nx_w1, nx_b1, nx_w2, nx_b2,
                                               nv_w1, nv_b1, nv_w2, nv_b2, gx, gv);
    edge_kernel<<<1024, 256, 0, stream>>>(x, h, v, row, col, edge_fea,
                                          em_w1, em_b1, em_w2, em_b2,
                                          cn_w1, cn_b1, cn_w2, cn_b2,
                                          cnt, totf, totmsg);
    node_out_kernel<<<1024, 256, 0, stream>>>(x, h, v, nn_w1, nn_b1, nn_w2, nn_b2,
                                              cnt, totf, totmsg, gx, gv,
                                              xout, vout, hout);
}